// Round 2
// baseline (965.635 us; speedup 1.0000x reference)
//
#include <hip/hip_runtime.h>
#include <stdint.h>

// ---------------------------------------------------------------------------
// Fused causal multi-head self-attention, bf16 MFMA pipeline.
// B=2, S=4096, D=1024, H=16, hd=64.  M = B*S = 8192.
//
// ws layout (bytes):
//   xb    @ 0         : 8192x1024 bf16   (16,777,216)
//   Wqkv  @ 16777216  : 3072x1024 bf16   ( 6,291,456)   rows n: [0,1024)=Wq, etc
//   Wob   @ 23068672  : 1024x1024 bf16   ( 2,097,152)
//   Q     @ 25165824  : [B,H,S,64] bf16  (16,777,216)
//   K     @ 41943040  : [B,H,S,64] bf16  (16,777,216)
//   Vt    @ 58720256  : [B,H,64,S] bf16  (16,777,216)   (V transposed)
//   attn  @ 75497472  : [8192,1024] bf16 (16,777,216)
//   total 92,274,688 bytes
// ---------------------------------------------------------------------------

typedef unsigned short u16;
typedef __attribute__((ext_vector_type(8))) __bf16 bf16x8;
typedef __attribute__((ext_vector_type(4))) float floatx4;
typedef __attribute__((ext_vector_type(8))) unsigned short ushortx8;

__device__ __forceinline__ u16 f2b(float x) {
  union { float f; unsigned int u; } v; v.f = x;
  unsigned int u = v.u;
  unsigned int r = (u + 0x7FFFu + ((u >> 16) & 1u)) >> 16;  // RNE
  return (u16)r;
}

__device__ __forceinline__ bf16x8 ld8(const u16* p) {
  return __builtin_bit_cast(bf16x8, *(const ushortx8*)p);
}

#define MFMA16(a, b, c) __builtin_amdgcn_mfma_f32_16x16x32_bf16((a), (b), (c), 0, 0, 0)

// ---------------------------------------------------------------------------
// fp32 -> bf16 conversion, 8 elements/thread
__global__ void cvt_kernel(const float* __restrict__ src, u16* __restrict__ dst, int n) {
  int i = (blockIdx.x * 256 + threadIdx.x) * 8;
  if (i >= n) return;
  floatx4 a = *(const floatx4*)(src + i);
  floatx4 b = *(const floatx4*)(src + i + 4);
  ushortx8 o;
  o[0] = f2b(a[0]); o[1] = f2b(a[1]); o[2] = f2b(a[2]); o[3] = f2b(a[3]);
  o[4] = f2b(b[0]); o[5] = f2b(b[1]); o[6] = f2b(b[2]); o[7] = f2b(b[3]);
  *(ushortx8*)(dst + i) = o;
}

// ---------------------------------------------------------------------------
// GEMM  C[M,N] = A[M,K] * B[N,K]^T   (both row-major, K contiguous), K=1024.
// 128x128 block tile, 4 waves in 2x2, each wave 64x64 (4x4 frags of 16x16x32).
// mode 0: QKV epilogue (scatter bf16 into Q,K and transposed Vt)
// mode 1: fp32 output epilogue (ld 1024)
__global__ __launch_bounds__(256) void gemm_bt(
    const u16* __restrict__ A, const u16* __restrict__ B, int mode,
    u16* __restrict__ Qb, u16* __restrict__ Kb, u16* __restrict__ Vtb,
    float* __restrict__ out) {
  constexpr int K = 1024;
  constexpr int LDT = 40;  // 32 + 8 pad: kills 8-way bank aliasing on frag reads
  __shared__ u16 At[128 * LDT];
  __shared__ u16 Bt[128 * LDT];
  int tid = threadIdx.x;
  int lane = tid & 63, w = tid >> 6;
  int quad = lane >> 4, l16 = lane & 15;
  int wr = w >> 1, wc = w & 1;

  floatx4 acc[4][4] = {};

  const u16* Ap = A + (size_t)(blockIdx.y * 128) * K;
  const u16* Bp = B + (size_t)(blockIdx.x * 128) * K;

  for (int k0 = 0; k0 < K; k0 += 32) {
    __syncthreads();  // protect previous iter's frag reads
    for (int j = 0; j < 2; ++j) {
      int c = tid + 256 * j;            // 512 chunks of 16B per tile
      int r = c >> 2, off = (c & 3) * 8;
      *(ushortx8*)(&At[r * LDT + off]) = *(const ushortx8*)(Ap + (size_t)r * K + k0 + off);
      *(ushortx8*)(&Bt[r * LDT + off]) = *(const ushortx8*)(Bp + (size_t)r * K + k0 + off);
    }
    __syncthreads();
    bf16x8 af[4], bfg[4];
    for (int i = 0; i < 4; ++i) af[i]  = ld8(&At[(wr * 64 + i * 16 + l16) * LDT + quad * 8]);
    for (int j = 0; j < 4; ++j) bfg[j] = ld8(&Bt[(wc * 64 + j * 16 + l16) * LDT + quad * 8]);
    for (int i = 0; i < 4; ++i)
      for (int j = 0; j < 4; ++j)
        acc[i][j] = MFMA16(af[i], bfg[j], acc[i][j]);
  }

  int rowbase = blockIdx.y * 128 + wr * 64 + quad * 4;
  int colbase = blockIdx.x * 128 + wc * 64 + l16;
  if (mode == 0) {
    for (int i = 0; i < 4; ++i)
      for (int j = 0; j < 4; ++j) {
        int gcol = colbase + j * 16;       // n in [0,3072); uniform 'which'/'h' per frag
        int which = gcol >> 10, within = gcol & 1023;
        int h = within >> 6, cc = within & 63;
        for (int r = 0; r < 4; ++r) {
          int grow = rowbase + i * 16 + r;
          int b = grow >> 12, s = grow & 4095;
          u16 v = f2b(acc[i][j][r]);
          if (which == 0)      Qb[((size_t)((b * 16 + h) * 4096 + s)) * 64 + cc] = v;
          else if (which == 1) Kb[((size_t)((b * 16 + h) * 4096 + s)) * 64 + cc] = v;
          else                 Vtb[((size_t)((b * 16 + h) * 64 + cc)) * 4096 + s] = v;
        }
      }
  } else {
    for (int i = 0; i < 4; ++i)
      for (int r = 0; r < 4; ++r) {
        int grow = rowbase + i * 16 + r;
        float* op = out + (size_t)grow * 1024 + colbase;
        for (int j = 0; j < 4; ++j) op[j * 16] = acc[i][j][r];
      }
  }
}

// ---------------------------------------------------------------------------
// Causal flash attention. Q,K: [B,H,S,64], Vt: [B,H,64,S], out attn: [8192,1024].
// grid (16, 32). Wave w of block bx owns 4 chunks of 16 q-rows:
//   chunk(mi) = mi*64 + bx*4 + w, rows = chunk*16 .. +15  (interleaved => balanced)
// K/V fragment loads are shared across the 4 chunks of the wave.
__global__ __launch_bounds__(256) void attn_kernel(
    const u16* __restrict__ Q, const u16* __restrict__ K,
    const u16* __restrict__ Vt, u16* __restrict__ attnb) {
  constexpr int LDP = 40;  // padded P row
  __shared__ u16 Plds[4][16 * LDP];
  int tid = threadIdx.x;
  int lane = tid & 63, w = tid >> 6;
  int quad = lane >> 4, l16 = lane & 15;
  int bh = blockIdx.y, bx = blockIdx.x;
  const u16* Qh = Q  + (size_t)bh * 4096 * 64;
  const u16* Kh = K  + (size_t)bh * 4096 * 64;
  const u16* Vh = Vt + (size_t)bh * 64 * 4096;

  int row0[4];
  bf16x8 qf[4][2];
  floatx4 o[4][4] = {};
  float m_i[4][4], l_i[4][4];
  for (int mi = 0; mi < 4; ++mi) {
    int chunk = mi * 64 + bx * 4 + w;  // 0..255, bijective
    row0[mi] = chunk * 16;
    qf[mi][0] = ld8(Qh + (size_t)(row0[mi] + l16) * 64 + quad * 8);
    qf[mi][1] = ld8(Qh + (size_t)(row0[mi] + l16) * 64 + 32 + quad * 8);
    for (int r = 0; r < 4; ++r) { m_i[mi][r] = -1e30f; l_i[mi][r] = 0.f; }
  }
  int kvend = row0[3] + 16;  // row0[3] is this wave's max chunk
  const float sc = 0.125f * 1.44269504088896f;  // 1/sqrt(64) * log2(e)

  for (int kv0 = 0; kv0 < kvend; kv0 += 32) {
    bf16x8 kf[2][2], vf[4];
    for (int nc = 0; nc < 2; ++nc) {
      kf[nc][0] = ld8(Kh + (size_t)(kv0 + nc * 16 + l16) * 64 + quad * 8);
      kf[nc][1] = ld8(Kh + (size_t)(kv0 + nc * 16 + l16) * 64 + 32 + quad * 8);
    }
    for (int nc = 0; nc < 4; ++nc)
      vf[nc] = ld8(Vh + (size_t)(nc * 16 + l16) * 4096 + kv0 + quad * 8);

    for (int mi = 0; mi < 4; ++mi) {
      int r0 = row0[mi];
      if (kv0 > r0 + 15) continue;  // wave-uniform skip: tile fully above diag
      floatx4 s0 = {0.f, 0.f, 0.f, 0.f}, s1 = {0.f, 0.f, 0.f, 0.f};
      s0 = MFMA16(qf[mi][0], kf[0][0], s0);
      s0 = MFMA16(qf[mi][1], kf[0][1], s0);
      s1 = MFMA16(qf[mi][0], kf[1][0], s1);
      s1 = MFMA16(qf[mi][1], kf[1][1], s1);
      bool needmask = (kv0 + 31 > r0);
      float s2[2][4];
      for (int nc = 0; nc < 2; ++nc)
        for (int r = 0; r < 4; ++r) {
          float v = (nc ? s1[r] : s0[r]) * sc;
          if (needmask) {
            int key = kv0 + nc * 16 + l16;
            int row = r0 + quad * 4 + r;
            if (key > row) v = -1e30f;
          }
          s2[nc][r] = v;
        }
      for (int r = 0; r < 4; ++r) {
        float rm = fmaxf(s2[0][r], s2[1][r]);
        rm = fmaxf(rm, __shfl_xor(rm, 1));
        rm = fmaxf(rm, __shfl_xor(rm, 2));
        rm = fmaxf(rm, __shfl_xor(rm, 4));
        rm = fmaxf(rm, __shfl_xor(rm, 8));
        float mn = fmaxf(m_i[mi][r], rm);
        float alpha = exp2f(m_i[mi][r] - mn);
        float p0 = exp2f(s2[0][r] - mn);
        float p1 = exp2f(s2[1][r] - mn);
        float ps = p0 + p1;
        ps += __shfl_xor(ps, 1);
        ps += __shfl_xor(ps, 2);
        ps += __shfl_xor(ps, 4);
        ps += __shfl_xor(ps, 8);
        l_i[mi][r] = l_i[mi][r] * alpha + ps;
        m_i[mi][r] = mn;
        for (int nc = 0; nc < 4; ++nc) o[mi][nc][r] *= alpha;
        Plds[w][(quad * 4 + r) * LDP + l16]      = f2b(p0);
        Plds[w][(quad * 4 + r) * LDP + 16 + l16] = f2b(p1);
      }
      // P: C-layout -> A-layout via per-wave LDS (compiler inserts lgkmcnt waits)
      bf16x8 pa = ld8(&Plds[w][l16 * LDP + quad * 8]);
      for (int nc = 0; nc < 4; ++nc) o[mi][nc] = MFMA16(pa, vf[nc], o[mi][nc]);
    }
  }

  int b = bh >> 4, h = bh & 15;
  for (int mi = 0; mi < 4; ++mi)
    for (int r = 0; r < 4; ++r) {
      float inv = 1.0f / l_i[mi][r];
      int s = row0[mi] + quad * 4 + r;
      size_t base = ((size_t)(b * 4096 + s)) * 1024 + h * 64;
      for (int nc = 0; nc < 4; ++nc)
        attnb[base + nc * 16 + l16] = f2b(o[mi][nc][r] * inv);
    }
}

// ---------------------------------------------------------------------------
extern "C" void kernel_launch(void* const* d_in, const int* in_sizes, int n_in,
                              void* d_out, int out_size, void* d_ws, size_t ws_size,
                              hipStream_t stream) {
  const float* x  = (const float*)d_in[0];
  const float* Wq = (const float*)d_in[1];
  const float* Wk = (const float*)d_in[2];
  const float* Wv = (const float*)d_in[3];
  const float* Wo = (const float*)d_in[4];
  char* ws = (char*)d_ws;
  u16* xb    = (u16*)(ws + 0);
  u16* Wqkv  = (u16*)(ws + 16777216);
  u16* Wob   = (u16*)(ws + 23068672);
  u16* Qb    = (u16*)(ws + 25165824);
  u16* Kb    = (u16*)(ws + 41943040);
  u16* Vtb   = (u16*)(ws + 58720256);
  u16* attnb = (u16*)(ws + 75497472);

  cvt_kernel<<<4096, 256, 0, stream>>>(x, xb, 8388608);
  cvt_kernel<<<512, 256, 0, stream>>>(Wq, Wqkv, 1048576);
  cvt_kernel<<<512, 256, 0, stream>>>(Wk, Wqkv + 1048576, 1048576);
  cvt_kernel<<<512, 256, 0, stream>>>(Wv, Wqkv + 2097152, 1048576);
  cvt_kernel<<<512, 256, 0, stream>>>(Wo, Wob, 1048576);

  gemm_bt<<<dim3(24, 64), 256, 0, stream>>>(xb, Wqkv, 0, Qb, Kb, Vtb, nullptr);
  attn_kernel<<<dim3(16, 32), 256, 0, stream>>>(Qb, Kb, Vtb, attnb);
  gemm_bt<<<dim3(8, 64), 256, 0, stream>>>(attnb, Wob, 1, nullptr, nullptr, nullptr,
                                           (float*)d_out);
}

// Round 3
// 725.614 us; speedup vs baseline: 1.3308x; 1.3308x over previous
//
#include <hip/hip_runtime.h>
#include <stdint.h>

// ---------------------------------------------------------------------------
// Fused causal multi-head self-attention, bf16 MFMA pipeline.
// B=2, S=4096, D=1024, H=16, hd=64.  M = B*S = 8192.
//
// ws layout (bytes):
//   xb    @ 0         : 8192x1024 bf16   (16,777,216)
//   Wqkv  @ 16777216  : 3072x1024 bf16   ( 6,291,456)
//   Wob   @ 23068672  : 1024x1024 bf16   ( 2,097,152)
//   Q     @ 25165824  : [B,H,S,64] bf16  (16,777,216)   pre-scaled by log2e/8
//   K     @ 41943040  : [B,H,S,64] bf16  (16,777,216)
//   Vt    @ 58720256  : [B,H,64,S] bf16  (16,777,216)   (V transposed)
//   attn  @ 75497472  : [8192,1024] bf16 (16,777,216)
// ---------------------------------------------------------------------------

typedef unsigned short u16;
typedef __attribute__((ext_vector_type(8))) __bf16 bf16x8;
typedef __attribute__((ext_vector_type(4))) float floatx4;
typedef __attribute__((ext_vector_type(8))) unsigned short ushortx8;

__device__ __forceinline__ u16 f2b(float x) {        // RNE
  union { float f; unsigned int u; } v; v.f = x;
  unsigned int u = v.u;
  return (u16)((u + 0x7FFFu + ((u >> 16) & 1u)) >> 16);
}
__device__ __forceinline__ u16 f2b_fast(float x) {   // round-half-up (p >= 0 only)
  union { float f; unsigned int u; } v; v.f = x;
  return (u16)((v.u + 0x8000u) >> 16);
}

__device__ __forceinline__ bf16x8 ld8(const u16* p) {
  return __builtin_bit_cast(bf16x8, *(const ushortx8*)p);
}

#define MFMA16(a, b, c) __builtin_amdgcn_mfma_f32_16x16x32_bf16((a), (b), (c), 0, 0, 0)

// DPP cross-lane (VALU pipe, not LDS): butterfly reduce over 16-lane groups.
template <int CTRL>
__device__ __forceinline__ float dpp_mv(float x) {
  return __builtin_bit_cast(float,
      __builtin_amdgcn_mov_dpp(__builtin_bit_cast(int, x), CTRL, 0xF, 0xF, true));
}
__device__ __forceinline__ float rmax16(float x) {
  x = fmaxf(x, dpp_mv<0xB1>(x));   // quad_perm xor1
  x = fmaxf(x, dpp_mv<0x4E>(x));   // quad_perm xor2
  x = fmaxf(x, dpp_mv<0x141>(x));  // row_half_mirror (8-group)
  x = fmaxf(x, dpp_mv<0x140>(x));  // row_mirror (16-group)
  return x;
}
__device__ __forceinline__ float rsum16(float x) {
  x += dpp_mv<0xB1>(x);
  x += dpp_mv<0x4E>(x);
  x += dpp_mv<0x141>(x);
  x += dpp_mv<0x140>(x);
  return x;
}

// ---------------------------------------------------------------------------
__global__ void cvt_kernel(const float* __restrict__ src, u16* __restrict__ dst, int n) {
  int i = (blockIdx.x * 256 + threadIdx.x) * 8;
  if (i >= n) return;
  floatx4 a = *(const floatx4*)(src + i);
  floatx4 b = *(const floatx4*)(src + i + 4);
  ushortx8 o;
  o[0] = f2b(a[0]); o[1] = f2b(a[1]); o[2] = f2b(a[2]); o[3] = f2b(a[3]);
  o[4] = f2b(b[0]); o[5] = f2b(b[1]); o[6] = f2b(b[2]); o[7] = f2b(b[3]);
  *(ushortx8*)(dst + i) = o;
}

// ---------------------------------------------------------------------------
// GEMM  C[M,N] = A[M,K] * B[N,K]^T, K=1024. 128x128 tile, 4 waves 2x2.
// mode 0: QKV epilogue (Q pre-scaled by log2e/8; scatter Q,K; V transposed)
// mode 1: fp32 output epilogue
__global__ __launch_bounds__(256) void gemm_bt(
    const u16* __restrict__ A, const u16* __restrict__ B, int mode,
    u16* __restrict__ Qb, u16* __restrict__ Kb, u16* __restrict__ Vtb,
    float* __restrict__ out) {
  constexpr int K = 1024;
  constexpr int LDT = 40;
  __shared__ u16 At[128 * LDT];
  __shared__ u16 Bt[128 * LDT];
  int tid = threadIdx.x;
  int lane = tid & 63, w = tid >> 6;
  int quad = lane >> 4, l16 = lane & 15;
  int wr = w >> 1, wc = w & 1;

  floatx4 acc[4][4] = {};
  const u16* Ap = A + (size_t)(blockIdx.y * 128) * K;
  const u16* Bp = B + (size_t)(blockIdx.x * 128) * K;

  for (int k0 = 0; k0 < K; k0 += 32) {
    __syncthreads();
    for (int j = 0; j < 2; ++j) {
      int c = tid + 256 * j;
      int r = c >> 2, off = (c & 3) * 8;
      *(ushortx8*)(&At[r * LDT + off]) = *(const ushortx8*)(Ap + (size_t)r * K + k0 + off);
      *(ushortx8*)(&Bt[r * LDT + off]) = *(const ushortx8*)(Bp + (size_t)r * K + k0 + off);
    }
    __syncthreads();
    bf16x8 af[4], bfg[4];
    for (int i = 0; i < 4; ++i) af[i]  = ld8(&At[(wr * 64 + i * 16 + l16) * LDT + quad * 8]);
    for (int j = 0; j < 4; ++j) bfg[j] = ld8(&Bt[(wc * 64 + j * 16 + l16) * LDT + quad * 8]);
    for (int i = 0; i < 4; ++i)
      for (int j = 0; j < 4; ++j)
        acc[i][j] = MFMA16(af[i], bfg[j], acc[i][j]);
  }

  int rowbase = blockIdx.y * 128 + wr * 64 + quad * 4;
  int colbase = blockIdx.x * 128 + wc * 64 + l16;
  if (mode == 0) {
    const float qscale = 0.18033688f;  // (1/sqrt(64)) * log2(e), folded into Q
    for (int i = 0; i < 4; ++i)
      for (int j = 0; j < 4; ++j) {
        int gcol = colbase + j * 16;
        int which = gcol >> 10, within = gcol & 1023;
        int h = within >> 6, cc = within & 63;
        for (int r = 0; r < 4; ++r) {
          int grow = rowbase + i * 16 + r;
          int b = grow >> 12, s = grow & 4095;
          float av = acc[i][j][r];
          if (which == 0)      Qb[((size_t)((b * 16 + h) * 4096 + s)) * 64 + cc] = f2b(av * qscale);
          else if (which == 1) Kb[((size_t)((b * 16 + h) * 4096 + s)) * 64 + cc] = f2b(av);
          else                 Vtb[((size_t)((b * 16 + h) * 64 + cc)) * 4096 + s] = f2b(av);
        }
      }
  } else {
    for (int i = 0; i < 4; ++i)
      for (int r = 0; r < 4; ++r) {
        int grow = rowbase + i * 16 + r;
        float* op = out + (size_t)grow * 1024 + colbase;
        for (int j = 0; j < 4; ++j) op[j * 16] = acc[i][j][r];
      }
  }
}

// ---------------------------------------------------------------------------
// Causal flash attention. Q pre-scaled. Q,K: [B,H,S,64], Vt: [B,H,64,S].
// grid (32, 32): 32 blocks/head x 4 waves; wave owns ONE 32-row q chunk:
//   chunk = (31-bx)*4 + w   (0..127; biggest trip counts dispatch first)
// kv tile = 64 keys/iteration.
__global__ __launch_bounds__(256) void attn_kernel(
    const u16* __restrict__ Q, const u16* __restrict__ K,
    const u16* __restrict__ Vt, u16* __restrict__ attnb) {
  constexpr int LDP = 72;  // 64 + 8 pad
  __shared__ u16 Plds[4][32 * LDP];
  int tid = threadIdx.x;
  int lane = tid & 63, w = tid >> 6;
  int quad = lane >> 4, l16 = lane & 15;
  int bh = blockIdx.y;
  int chunk = (31 - (int)blockIdx.x) * 4 + w;  // 0..127
  int r0 = chunk * 32;
  const u16* Qh = Q  + (size_t)bh * 4096 * 64;
  const u16* Kh = K  + (size_t)bh * 4096 * 64;
  const u16* Vh = Vt + (size_t)bh * 64 * 4096;
  u16* Pw = &Plds[w][0];

  bf16x8 qf[2][2];
  for (int mi = 0; mi < 2; ++mi)
    for (int p = 0; p < 2; ++p)
      qf[mi][p] = ld8(Qh + (size_t)(r0 + mi * 16 + l16) * 64 + p * 32 + quad * 8);

  floatx4 o[2][4] = {};
  float m[2][4], lp[2][4];
  for (int mi = 0; mi < 2; ++mi)
    for (int r = 0; r < 4; ++r) { m[mi][r] = -1e30f; lp[mi][r] = 0.f; }

  int kvend = r0 + 32;
  for (int kv0 = 0; kv0 < kvend; kv0 += 64) {
    // ---- QK^T: 32x64 scores ----
    floatx4 s[2][4] = {};
    for (int n = 0; n < 4; ++n)
      for (int p = 0; p < 2; ++p) {
        bf16x8 kf = ld8(Kh + (size_t)(kv0 + n * 16 + l16) * 64 + p * 32 + quad * 8);
        s[0][n] = MFMA16(qf[0][p], kf, s[0][n]);
        s[1][n] = MFMA16(qf[1][p], kf, s[1][n]);
      }
    // ---- causal mask (only diagonal/partial tiles; wave-uniform branch) ----
    if (kv0 + 63 > r0) {
      for (int mi = 0; mi < 2; ++mi)
        for (int n = 0; n < 4; ++n) {
          int key = kv0 + n * 16 + l16;
          for (int r = 0; r < 4; ++r) {
            int row = r0 + mi * 16 + quad * 4 + r;
            if (key > row) s[mi][n][r] = -1e30f;
          }
        }
    }
    // ---- online softmax (exp2 domain; scale pre-folded into Q) ----
    float mn[2][4], ls[2][4];
    bool ch = false;
    for (int mi = 0; mi < 2; ++mi)
      for (int r = 0; r < 4; ++r) {
        float rm = fmaxf(fmaxf(s[mi][0][r], s[mi][1][r]),
                         fmaxf(s[mi][2][r], s[mi][3][r]));
        rm = rmax16(rm);
        float mo = m[mi][r];
        float mx = fmaxf(mo, rm);
        mn[mi][r] = mx;
        ch |= (mx > mo);
        float p0 = exp2f(s[mi][0][r] - mx);
        float p1 = exp2f(s[mi][1][r] - mx);
        float p2 = exp2f(s[mi][2][r] - mx);
        float p3 = exp2f(s[mi][3][r] - mx);
        ls[mi][r] = (p0 + p1) + (p2 + p3);
        int rr = (mi * 16 + quad * 4 + r) * LDP + l16;
        Pw[rr]      = f2b_fast(p0);
        Pw[rr + 16] = f2b_fast(p1);
        Pw[rr + 32] = f2b_fast(p2);
        Pw[rr + 48] = f2b_fast(p3);
      }
    if (__any((int)ch)) {
      for (int mi = 0; mi < 2; ++mi)
        for (int r = 0; r < 4; ++r) {
          float al = exp2f(m[mi][r] - mn[mi][r]);
          m[mi][r] = mn[mi][r];
          lp[mi][r] = lp[mi][r] * al + ls[mi][r];
          for (int h = 0; h < 4; ++h) o[mi][h][r] *= al;
        }
    } else {
      for (int mi = 0; mi < 2; ++mi)
        for (int r = 0; r < 4; ++r) lp[mi][r] += ls[mi][r];
    }
    // ---- P (C-layout -> A-layout via per-wave LDS), then PV ----
    bf16x8 pa[2][2];
    for (int mi = 0; mi < 2; ++mi)
      for (int p = 0; p < 2; ++p)
        pa[mi][p] = ld8(&Pw[(mi * 16 + l16) * LDP + p * 32 + quad * 8]);
    for (int h = 0; h < 4; ++h)
      for (int p = 0; p < 2; ++p) {
        bf16x8 vf = ld8(Vh + (size_t)(h * 16 + l16) * 4096 + kv0 + p * 32 + quad * 8);
        o[0][h] = MFMA16(pa[0][p], vf, o[0][h]);
        o[1][h] = MFMA16(pa[1][p], vf, o[1][h]);
      }
  }

  int b = bh >> 4, hh = bh & 15;
  for (int mi = 0; mi < 2; ++mi)
    for (int r = 0; r < 4; ++r) {
      float l = rsum16(lp[mi][r]);
      float inv = 1.0f / l;
      int srow = r0 + mi * 16 + quad * 4 + r;
      size_t base = ((size_t)(b * 4096 + srow)) * 1024 + hh * 64;
      for (int h = 0; h < 4; ++h)
        attnb[base + h * 16 + l16] = f2b(o[mi][h][r] * inv);
    }
}

// ---------------------------------------------------------------------------
extern "C" void kernel_launch(void* const* d_in, const int* in_sizes, int n_in,
                              void* d_out, int out_size, void* d_ws, size_t ws_size,
                              hipStream_t stream) {
  const float* x  = (const float*)d_in[0];
  const float* Wq = (const float*)d_in[1];
  const float* Wk = (const float*)d_in[2];
  const float* Wv = (const float*)d_in[3];
  const float* Wo = (const float*)d_in[4];
  char* ws = (char*)d_ws;
  u16* xb    = (u16*)(ws + 0);
  u16* Wqkv  = (u16*)(ws + 16777216);
  u16* Wob   = (u16*)(ws + 23068672);
  u16* Qb    = (u16*)(ws + 25165824);
  u16* Kb    = (u16*)(ws + 41943040);
  u16* Vtb   = (u16*)(ws + 58720256);
  u16* attnb = (u16*)(ws + 75497472);

  cvt_kernel<<<4096, 256, 0, stream>>>(x, xb, 8388608);
  cvt_kernel<<<512, 256, 0, stream>>>(Wq, Wqkv, 1048576);
  cvt_kernel<<<512, 256, 0, stream>>>(Wk, Wqkv + 1048576, 1048576);
  cvt_kernel<<<512, 256, 0, stream>>>(Wv, Wqkv + 2097152, 1048576);
  cvt_kernel<<<512, 256, 0, stream>>>(Wo, Wob, 1048576);

  gemm_bt<<<dim3(24, 64), 256, 0, stream>>>(xb, Wqkv, 0, Qb, Kb, Vtb, nullptr);
  attn_kernel<<<dim3(32, 32), 256, 0, stream>>>(Qb, Kb, Vtb, attnb);
  gemm_bt<<<dim3(8, 64), 256, 0, stream>>>(attnb, Wob, 1, nullptr, nullptr, nullptr,
                                           (float*)d_out);
}

// Round 4
// 514.896 us; speedup vs baseline: 1.8754x; 1.4092x over previous
//
#include <hip/hip_runtime.h>
#include <stdint.h>

// ---------------------------------------------------------------------------
// Fused causal multi-head self-attention, bf16 MFMA pipeline.
// B=2, S=4096, D=1024, H=16, hd=64.  M = B*S = 8192.
//
// ws layout (bytes):
//   xb    @ 0         : 8192x1024 bf16   (16,777,216)
//   Wqkv  @ 16777216  : 3072x1024 bf16   ( 6,291,456)
//   Wob   @ 23068672  : 1024x1024 bf16   ( 2,097,152)
//   Q     @ 25165824  : [B,H,S,64] bf16  (16,777,216)   pre-scaled by log2e/8
//   K     @ 41943040  : [B,H,S,64] bf16  (16,777,216)
//   Vt    @ 58720256  : [B,H,64,S] bf16  (16,777,216)   (V transposed)
//   attn  @ 75497472  : [8192,1024] bf16 (16,777,216)
// ---------------------------------------------------------------------------

typedef unsigned short u16;
typedef __attribute__((ext_vector_type(8))) __bf16 bf16x8;
typedef __attribute__((ext_vector_type(4))) float floatx4;
typedef __attribute__((ext_vector_type(8))) unsigned short ushortx8;

__device__ __forceinline__ u16 f2b(float x) {        // RNE
  union { float f; unsigned int u; } v; v.f = x;
  unsigned int u = v.u;
  return (u16)((u + 0x7FFFu + ((u >> 16) & 1u)) >> 16);
}
__device__ __forceinline__ u16 f2b_fast(float x) {   // round-half-up (p >= 0 only)
  union { float f; unsigned int u; } v; v.f = x;
  return (u16)((v.u + 0x8000u) >> 16);
}

__device__ __forceinline__ bf16x8 ld8(const u16* p) {
  return __builtin_bit_cast(bf16x8, *(const ushortx8*)p);
}

#define MFMA16(a, b, c) __builtin_amdgcn_mfma_f32_16x16x32_bf16((a), (b), (c), 0, 0, 0)

#if __has_builtin(__builtin_amdgcn_exp2f)
#define EXP2(x) __builtin_amdgcn_exp2f(x)
#else
#define EXP2(x) exp2f(x)
#endif

// DPP cross-lane (VALU pipe, not LDS): butterfly reduce over 16-lane groups.
template <int CTRL>
__device__ __forceinline__ float dpp_mv(float x) {
  return __builtin_bit_cast(float,
      __builtin_amdgcn_mov_dpp(__builtin_bit_cast(int, x), CTRL, 0xF, 0xF, true));
}
__device__ __forceinline__ float rmax16(float x) {
  x = fmaxf(x, dpp_mv<0xB1>(x));   // quad_perm xor1
  x = fmaxf(x, dpp_mv<0x4E>(x));   // quad_perm xor2
  x = fmaxf(x, dpp_mv<0x141>(x));  // row_half_mirror (8-group)
  x = fmaxf(x, dpp_mv<0x140>(x));  // row_mirror (16-group)
  return x;
}
__device__ __forceinline__ float rsum16(float x) {
  x += dpp_mv<0xB1>(x);
  x += dpp_mv<0x4E>(x);
  x += dpp_mv<0x141>(x);
  x += dpp_mv<0x140>(x);
  return x;
}

// ---------------------------------------------------------------------------
__global__ void cvt_kernel(const float* __restrict__ src, u16* __restrict__ dst, int n) {
  int i = (blockIdx.x * 256 + threadIdx.x) * 8;
  if (i >= n) return;
  floatx4 a = *(const floatx4*)(src + i);
  floatx4 b = *(const floatx4*)(src + i + 4);
  ushortx8 o;
  o[0] = f2b(a[0]); o[1] = f2b(a[1]); o[2] = f2b(a[2]); o[3] = f2b(a[3]);
  o[4] = f2b(b[0]); o[5] = f2b(b[1]); o[6] = f2b(b[2]); o[7] = f2b(b[3]);
  *(ushortx8*)(dst + i) = o;
}

// ---------------------------------------------------------------------------
// GEMM  C[M,N] = A[M,K] * B[N,K]^T, K=1024. 128x128 tile, 4 waves 2x2.
// mode 0: QKV epilogue (Q pre-scaled by log2e/8; scatter Q,K; V transposed)
// mode 1: fp32 output epilogue
__global__ __launch_bounds__(256) void gemm_bt(
    const u16* __restrict__ A, const u16* __restrict__ B, int mode,
    u16* __restrict__ Qb, u16* __restrict__ Kb, u16* __restrict__ Vtb,
    float* __restrict__ out) {
  constexpr int K = 1024;
  constexpr int LDT = 40;
  __shared__ u16 At[128 * LDT];
  __shared__ u16 Bt[128 * LDT];
  int tid = threadIdx.x;
  int lane = tid & 63, w = tid >> 6;
  int quad = lane >> 4, l16 = lane & 15;
  int wr = w >> 1, wc = w & 1;

  floatx4 acc[4][4] = {};
  const u16* Ap = A + (size_t)(blockIdx.y * 128) * K;
  const u16* Bp = B + (size_t)(blockIdx.x * 128) * K;

  for (int k0 = 0; k0 < K; k0 += 32) {
    __syncthreads();
    for (int j = 0; j < 2; ++j) {
      int c = tid + 256 * j;
      int r = c >> 2, off = (c & 3) * 8;
      *(ushortx8*)(&At[r * LDT + off]) = *(const ushortx8*)(Ap + (size_t)r * K + k0 + off);
      *(ushortx8*)(&Bt[r * LDT + off]) = *(const ushortx8*)(Bp + (size_t)r * K + k0 + off);
    }
    __syncthreads();
    bf16x8 af[4], bfg[4];
    for (int i = 0; i < 4; ++i) af[i]  = ld8(&At[(wr * 64 + i * 16 + l16) * LDT + quad * 8]);
    for (int j = 0; j < 4; ++j) bfg[j] = ld8(&Bt[(wc * 64 + j * 16 + l16) * LDT + quad * 8]);
    for (int i = 0; i < 4; ++i)
      for (int j = 0; j < 4; ++j)
        acc[i][j] = MFMA16(af[i], bfg[j], acc[i][j]);
  }

  int rowbase = blockIdx.y * 128 + wr * 64 + quad * 4;
  int colbase = blockIdx.x * 128 + wc * 64 + l16;
  if (mode == 0) {
    const float qscale = 0.18033688f;  // (1/sqrt(64)) * log2(e), folded into Q
    for (int i = 0; i < 4; ++i)
      for (int j = 0; j < 4; ++j) {
        int gcol = colbase + j * 16;
        int which = gcol >> 10, within = gcol & 1023;
        int h = within >> 6, cc = within & 63;
        for (int r = 0; r < 4; ++r) {
          int grow = rowbase + i * 16 + r;
          int b = grow >> 12, s = grow & 4095;
          float av = acc[i][j][r];
          if (which == 0)      Qb[((size_t)((b * 16 + h) * 4096 + s)) * 64 + cc] = f2b(av * qscale);
          else if (which == 1) Kb[((size_t)((b * 16 + h) * 4096 + s)) * 64 + cc] = f2b(av);
          else                 Vtb[((size_t)((b * 16 + h) * 64 + cc)) * 4096 + s] = f2b(av);
        }
      }
  } else {
    for (int i = 0; i < 4; ++i)
      for (int r = 0; r < 4; ++r) {
        int grow = rowbase + i * 16 + r;
        float* op = out + (size_t)grow * 1024 + colbase;
        for (int j = 0; j < 4; ++j) op[j * 16] = acc[i][j][r];
      }
  }
}

// ---------------------------------------------------------------------------
// Causal flash attention, balanced paired chunks. Q pre-scaled by log2e/8.
// Q,K: [B,H,S,64], Vt: [B,H,64,S], out attn: [8192,1024].
// grid (16, 32), 4 waves/block. task = bx*4+w in [0,64):
//   chunk lo = task      (rows 32*task   .. +31), active while kv0 < 32*task+32
//   chunk hi = 127-task  (rows 4064-32*task .. +31), active whole loop
// Trip count = ceil((4096-32t)/64) ~ const; total work/wave exactly balanced.
// K/V fragment loads shared between both chunks (2x reuse).
__global__ __launch_bounds__(256, 2) void attn_kernel(
    const u16* __restrict__ Q, const u16* __restrict__ K,
    const u16* __restrict__ Vt, u16* __restrict__ attnb) {
  constexpr int LDP = 72;  // 64 + 8 pad
  __shared__ u16 Plds[4][2][32 * LDP];
  int tid = threadIdx.x;
  int lane = tid & 63, w = tid >> 6;
  int quad = lane >> 4, l16 = lane & 15;
  int bh = blockIdx.y;
  int task = blockIdx.x * 4 + w;  // 0..63
  int r0[2];
  r0[0] = task * 32;          // lo chunk
  r0[1] = 4064 - task * 32;   // hi chunk = (127-task)*32
  const u16* Qh = Q  + (size_t)bh * 4096 * 64;
  const u16* Kh = K  + (size_t)bh * 4096 * 64;
  const u16* Vh = Vt + (size_t)bh * 64 * 4096;

  bf16x8 qf[2][2][2];          // [chunk][mi][p]
  floatx4 o[2][2][4] = {};     // [chunk][mi][h]
  float m[2][2][4], lp[2][2][4];
  for (int c = 0; c < 2; ++c)
    for (int mi = 0; mi < 2; ++mi) {
      for (int p = 0; p < 2; ++p)
        qf[c][mi][p] = ld8(Qh + (size_t)(r0[c] + mi * 16 + l16) * 64 + p * 32 + quad * 8);
      for (int r = 0; r < 4; ++r) { m[c][mi][r] = -1e30f; lp[c][mi][r] = 0.f; }
    }

  int kvend_l = r0[0] + 32;
  int kvend_h = r0[1] + 32;
  for (int kv0 = 0; kv0 < kvend_h; kv0 += 64) {
    bool doLo = (kv0 < kvend_l);  // wave-uniform

    // ---- QK^T for both chunks, shared K fragments ----
    floatx4 s[2][2][4] = {};     // [chunk][mi][n]
    for (int n = 0; n < 4; ++n) {
      const u16* kp = Kh + (size_t)(kv0 + n * 16 + l16) * 64;
      bf16x8 kf0 = ld8(kp + quad * 8);
      bf16x8 kf1 = ld8(kp + 32 + quad * 8);
      for (int mi = 0; mi < 2; ++mi) {
        s[1][mi][n] = MFMA16(qf[1][mi][0], kf0, s[1][mi][n]);
        s[1][mi][n] = MFMA16(qf[1][mi][1], kf1, s[1][mi][n]);
      }
      if (doLo)
        for (int mi = 0; mi < 2; ++mi) {
          s[0][mi][n] = MFMA16(qf[0][mi][0], kf0, s[0][mi][n]);
          s[0][mi][n] = MFMA16(qf[0][mi][1], kf1, s[0][mi][n]);
        }
    }

    // ---- per-chunk mask + online softmax + P store ----
    for (int c = 0; c < 2; ++c) {
      if (c == 0 && !doLo) continue;
      if (kv0 + 63 > r0[c]) {  // diagonal/partial tile only
        for (int mi = 0; mi < 2; ++mi)
          for (int n = 0; n < 4; ++n) {
            int key = kv0 + n * 16 + l16;
            for (int r = 0; r < 4; ++r)
              if (key > r0[c] + mi * 16 + quad * 4 + r) s[c][mi][n][r] = -1e30f;
          }
      }
      u16* Pw = &Plds[w][c][0];
      float mn_[2][4], ls_[2][4];
      bool ch = false;
      for (int mi = 0; mi < 2; ++mi)
        for (int r = 0; r < 4; ++r) {
          float rm = fmaxf(fmaxf(s[c][mi][0][r], s[c][mi][1][r]),
                           fmaxf(s[c][mi][2][r], s[c][mi][3][r]));
          rm = rmax16(rm);
          float mo = m[c][mi][r];
          float mx = fmaxf(mo, rm);
          mn_[mi][r] = mx;
          ch |= (mx > mo);
          float p0 = EXP2(s[c][mi][0][r] - mx);
          float p1 = EXP2(s[c][mi][1][r] - mx);
          float p2 = EXP2(s[c][mi][2][r] - mx);
          float p3 = EXP2(s[c][mi][3][r] - mx);
          ls_[mi][r] = (p0 + p1) + (p2 + p3);
          int rr = (mi * 16 + quad * 4 + r) * LDP + l16;
          Pw[rr]      = f2b_fast(p0);
          Pw[rr + 16] = f2b_fast(p1);
          Pw[rr + 32] = f2b_fast(p2);
          Pw[rr + 48] = f2b_fast(p3);
        }
      if (__any((int)ch)) {
        for (int mi = 0; mi < 2; ++mi)
          for (int r = 0; r < 4; ++r) {
            float al = EXP2(m[c][mi][r] - mn_[mi][r]);
            m[c][mi][r] = mn_[mi][r];
            lp[c][mi][r] = lp[c][mi][r] * al + ls_[mi][r];
            for (int h = 0; h < 4; ++h) o[c][mi][h][r] *= al;
          }
      } else {
        for (int mi = 0; mi < 2; ++mi)
          for (int r = 0; r < 4; ++r) lp[c][mi][r] += ls_[mi][r];
      }
    }

    // ---- P (C-layout -> A-layout via per-wave LDS), PV with shared V ----
    bf16x8 pa[2][2][2];
    for (int c = 0; c < 2; ++c) {
      if (c == 0 && !doLo) continue;
      for (int mi = 0; mi < 2; ++mi)
        for (int p = 0; p < 2; ++p)
          pa[c][mi][p] = ld8(&Plds[w][c][(mi * 16 + l16) * LDP + p * 32 + quad * 8]);
    }
    for (int h = 0; h < 4; ++h) {
      const u16* vp = Vh + (size_t)(h * 16 + l16) * 4096 + kv0;
      bf16x8 vf0 = ld8(vp + quad * 8);
      bf16x8 vf1 = ld8(vp + 32 + quad * 8);
      for (int mi = 0; mi < 2; ++mi) {
        o[1][mi][h] = MFMA16(pa[1][mi][0], vf0, o[1][mi][h]);
        o[1][mi][h] = MFMA16(pa[1][mi][1], vf1, o[1][mi][h]);
      }
      if (doLo)
        for (int mi = 0; mi < 2; ++mi) {
          o[0][mi][h] = MFMA16(pa[0][mi][0], vf0, o[0][mi][h]);
          o[0][mi][h] = MFMA16(pa[0][mi][1], vf1, o[0][mi][h]);
        }
    }
  }

  int b = bh >> 4, hh = bh & 15;
  for (int c = 0; c < 2; ++c)
    for (int mi = 0; mi < 2; ++mi)
      for (int r = 0; r < 4; ++r) {
        float inv = 1.0f / rsum16(lp[c][mi][r]);
        int srow = r0[c] + mi * 16 + quad * 4 + r;
        size_t base = ((size_t)(b * 4096 + srow)) * 1024 + hh * 64;
        for (int h = 0; h < 4; ++h)
          attnb[base + h * 16 + l16] = f2b(o[c][mi][h][r] * inv);
      }
}

// ---------------------------------------------------------------------------
extern "C" void kernel_launch(void* const* d_in, const int* in_sizes, int n_in,
                              void* d_out, int out_size, void* d_ws, size_t ws_size,
                              hipStream_t stream) {
  const float* x  = (const float*)d_in[0];
  const float* Wq = (const float*)d_in[1];
  const float* Wk = (const float*)d_in[2];
  const float* Wv = (const float*)d_in[3];
  const float* Wo = (const float*)d_in[4];
  char* ws = (char*)d_ws;
  u16* xb    = (u16*)(ws + 0);
  u16* Wqkv  = (u16*)(ws + 16777216);
  u16* Wob   = (u16*)(ws + 23068672);
  u16* Qb    = (u16*)(ws + 25165824);
  u16* Kb    = (u16*)(ws + 41943040);
  u16* Vtb   = (u16*)(ws + 58720256);
  u16* attnb = (u16*)(ws + 75497472);

  cvt_kernel<<<4096, 256, 0, stream>>>(x, xb, 8388608);
  cvt_kernel<<<512, 256, 0, stream>>>(Wq, Wqkv, 1048576);
  cvt_kernel<<<512, 256, 0, stream>>>(Wk, Wqkv + 1048576, 1048576);
  cvt_kernel<<<512, 256, 0, stream>>>(Wv, Wqkv + 2097152, 1048576);
  cvt_kernel<<<512, 256, 0, stream>>>(Wo, Wob, 1048576);

  gemm_bt<<<dim3(24, 64), 256, 0, stream>>>(xb, Wqkv, 0, Qb, Kb, Vtb, nullptr);
  attn_kernel<<<dim3(16, 32), 256, 0, stream>>>(Qb, Kb, Vtb, attnb);
  gemm_bt<<<dim3(8, 64), 256, 0, stream>>>(attnb, Wob, 1, nullptr, nullptr, nullptr,
                                           (float*)d_out);
}